// Round 10
// baseline (136.667 us; speedup 1.0000x reference)
//
#include <hip/hip_runtime.h>

#define NFR 500   // n_frames
#define NFQ 320   // n_freq
#define NB  2     // batch
#define NC  6     // n_chan
#define NS  4     // n_src
#define NBK 2     // n_chan - n_src
#define NT  4     // n_taps
#define NDLY 1    // n_delay
#define EPSF 1e-3f
#define TINYF 1e-20f

#define NP   512            // padded frame count (8 x 64 lanes)
#define XPAD 8              // leading zero-pad for shifted X reads
#define XLEN (XPAD + NP)

typedef float f2 __attribute__((ext_vector_type(2)));

__device__ __forceinline__ f2 mk2(float r, float i){ f2 t; t.x = r; t.y = i; return t; }
// complex ops on (re,im) pairs — select v_pk_* packed fp32
__device__ __forceinline__ f2 cmul(f2 a, f2 b){ return a.xx*b + a.yy*mk2(-b.y, b.x); }
__device__ __forceinline__ f2 cmulc(f2 a, f2 b){ return b.xx*a + b.yy*mk2(a.y, -a.x); } // a*conj(b)
__device__ __forceinline__ f2 conjc(f2 a){ return mk2(a.x, -a.y); }
__device__ __forceinline__ float cmag2(f2 a){ return a.x*a.x + a.y*a.y; }
__device__ __forceinline__ f2 cinv(f2 a){ float m = a.x*a.x + a.y*a.y; return mk2(a.x/m, -a.y/m); }

// wave64 sum-reduce via DPP (VALU latency); result uniform via readlane(63)
#define DPPF(x, ctrl) __int_as_float(__builtin_amdgcn_mov_dpp(__float_as_int(x), (ctrl), 0xF, 0xF, true))
__device__ __forceinline__ float wred64(float x){
  x += DPPF(x, 0x111);   // row_shr:1
  x += DPPF(x, 0x112);   // row_shr:2
  x += DPPF(x, 0x114);   // row_shr:4
  x += DPPF(x, 0x118);   // row_shr:8
  x += DPPF(x, 0x142);   // row_bcast:15
  x += DPPF(x, 0x143);   // row_bcast:31
  return __int_as_float(__builtin_amdgcn_readlane(__float_as_int(x), 63));
}

// ---------------------------------------------------------------------------
// final w from X (iteration 0: Y == X[:4]); 8 blocks, one per (b,s)
// ---------------------------------------------------------------------------
__global__ __launch_bounds__(512) void k_wX(const float* __restrict__ Xr,
                                            const float* __restrict__ Xi,
                                            float* __restrict__ wg)
{
  const int bs = blockIdx.x;
  const int n  = threadIdx.x;
  if (n >= NFR) return;
  const int b = bs / NS, s = bs % NS;
  const size_t rowb = ((size_t)(b*NC + s)*NFQ)*NFR + n;
  float a0 = 0.f, a1 = 0.f, a2 = 0.f, a3 = 0.f;
#pragma unroll 4
  for (int f = 0; f < NFQ; f += 4) {
    float r0 = Xr[rowb + (size_t)(f+0)*NFR], i0 = Xi[rowb + (size_t)(f+0)*NFR];
    float r1 = Xr[rowb + (size_t)(f+1)*NFR], i1 = Xi[rowb + (size_t)(f+1)*NFR];
    float r2 = Xr[rowb + (size_t)(f+2)*NFR], i2 = Xi[rowb + (size_t)(f+2)*NFR];
    float r3 = Xr[rowb + (size_t)(f+3)*NFR], i3 = Xi[rowb + (size_t)(f+3)*NFR];
    a0 += r0*r0 + i0*i0;  a1 += r1*r1 + i1*i1;
    a2 += r2*r2 + i2*i2;  a3 += r3*r3 + i3*i3;
  }
  float acc = (a0 + a1) + (a2 + a3);
  wg[bs*NFR + n] = 1.0f / fmaxf(acc * (1.0f/(float)NFQ), EPSF);
}

// ---------------------------------------------------------------------------
// final w from Y (between iterations); 8 blocks, one per (b,s)
// ---------------------------------------------------------------------------
__global__ __launch_bounds__(512) void k_wY(const f2* __restrict__ Yg,
                                            float* __restrict__ wg)
{
  const int bs = blockIdx.x;
  const int n  = threadIdx.x;
  if (n >= NFR) return;
  const f2* row = Yg + (size_t)bs*NFQ*NFR + n;
  f2 a0 = mk2(0.f,0.f), a1 = mk2(0.f,0.f), a2 = mk2(0.f,0.f), a3 = mk2(0.f,0.f);
#pragma unroll 4
  for (int f = 0; f < NFQ; f += 4) {
    f2 y0 = row[(size_t)(f+0)*NFR];
    f2 y1 = row[(size_t)(f+1)*NFR];
    f2 y2 = row[(size_t)(f+2)*NFR];
    f2 y3 = row[(size_t)(f+3)*NFR];
    a0 += y0*y0; a1 += y1*y1; a2 += y2*y2; a3 += y3*y3;
  }
  f2 s2 = (a0 + a1) + (a2 + a3);
  wg[bs*NFR + n] = 1.0f / fmaxf((s2.x + s2.y) * (1.0f/(float)NFQ), EPSF);
}

// ---------------------------------------------------------------------------
// one full iss_updates iteration per (b,f) block. Y,w in registers (wave-owned
// channel); X zero-padded in LDS; packed-fp32 math; DPP reductions; H dead.
// NO register-array dynamic indexing anywhere (scratch-free): bak-round v is
// six NAMED registers vl0..vl5; init GJ runs in-place on LDS sB.
// ---------------------------------------------------------------------------
__global__ __launch_bounds__(256, 3) void k_iter(
  const float* __restrict__ Xr, const float* __restrict__ Xi,
  f2* __restrict__ Yg, f2* __restrict__ Zg,
  f2* __restrict__ Wg, f2* __restrict__ Jg, f2* __restrict__ Ag,
  const float* __restrict__ wg, float* __restrict__ outR,
  const int first, const int last)
{
  __shared__ f2 sXp[NC][XLEN];   // front/back zero-padded X
  __shared__ f2 sZ[NBK][NP];
  __shared__ f2 sS[NP];
  __shared__ f2 sW[NS][NC];
  __shared__ f2 sJ[NBK][NS];
  __shared__ f2 sA[NS][NS];
  __shared__ f2 sB[NS][2*NS];    // GJ scratch (LDS); also C_XX staging when first
  __shared__ f2 sv[NC], sg[NC], sgo[NS];
  __shared__ float sd[NC];
  __shared__ f2 sp[NC];
  __shared__ f2 sAv[NS], sgA[NS], sWsrc[NC];

  const int bf = blockIdx.x;
  const int b = bf / NFQ, f = bf % NFQ;
  const int tid = threadIdx.x, wv = tid >> 6, lane = tid & 63;

  f2 yreg[8];   // wave-owned channel wv
  float wreg[8];

  // ---- stage X (zero-padded both ends)
  for (int c = 0; c < NC; ++c) {
    const size_t base = ((size_t)(b*NC + c)*NFQ + f)*NFR;
    for (int j = tid; j < XLEN; j += 256) {
      int n = j - XPAD;
      sXp[c][j] = (n >= 0 && n < NFR) ? mk2(Xr[base+n], Xi[base+n]) : mk2(0.f,0.f);
    }
  }

  if (first) {
    __syncthreads();   // X staged
    // ---- C_XX[s][d] partials into sB (s<4, d<6); W/A = eye
    for (int p = wv; p < NS*NC; p += 4) {
      int s = p / NC, d = p % NC;
      f2 ar2 = mk2(0.f,0.f), ai2 = mk2(0.f,0.f);
#pragma unroll
      for (int i = 0; i < 8; ++i) {
        int n = lane + 64*i;                     // padded zeros harmless
        f2 xs = sXp[s][XPAD+n], xd = sXp[d][XPAD+n];
        ar2 += xs * xd;
        ai2 += xs.yx * mk2(xd.x, -xd.y);
      }
      float ar = wred64(ar2.x + ar2.y), ai = wred64(ai2.x + ai2.y);
      if (lane == 0) sB[s][d] = mk2(ar*(1.f/NFR), ai*(1.f/NFR));
    }
    if (tid >= 192 && tid < 192 + NS*NC) {
      int t = tid - 192; sW[t/NC][t%NC] = (t/NC == t%NC) ? mk2(1.f,0.f) : mk2(0.f,0.f);
    } else if (tid >= 224 && tid < 224 + NS*NS) {
      int t = tid - 224; sA[t/NS][t%NS] = (t/NS == t%NS) ? mk2(1.f,0.f) : mk2(0.f,0.f);
    }
    __syncthreads();
    if (tid == 0) {   // diag-loaded GJ solve IN-PLACE on LDS sB -> J
      float dsum = 0.f;
      for (int s = 0; s < NS; ++s) dsum += sqrtf(cmag2(sB[s][s]));
      float load = fmaxf(dsum*1e-5f, 1e-5f);
      for (int s = 0; s < NS; ++s) sB[s][s].x += load;
      for (int col = 0; col < NS; ++col) {
        int piv = col; float best = cmag2(sB[col][col]);
        for (int r = col+1; r < NS; ++r) { float m = cmag2(sB[r][col]); if (m > best){best=m; piv=r;} }
        if (piv != col) for (int k = col; k < NC; ++k) { f2 t=sB[col][k]; sB[col][k]=sB[piv][k]; sB[piv][k]=t; }
        f2 ip = cinv(sB[col][col]);
        for (int k = col; k < NC; ++k) sB[col][k] = cmul(sB[col][k], ip);
        for (int r = 0; r < NS; ++r) if (r != col) {
          f2 fac = sB[r][col];
          for (int k = col; k < NC; ++k) sB[r][k] -= cmul(fac, sB[col][k]);
        }
      }
      for (int k = 0; k < NBK; ++k)
        for (int s = 0; s < NS; ++s) sJ[k][s] = conjc(sB[s][NS+k]);
    }
    __syncthreads();   // sJ ready
    // ---- Z = J X - X[4:] (LDS), Y = X[:4] (regs), w from wg
    for (int n = tid; n < NP; n += 256) {
      f2 x0 = sXp[0][XPAD+n], x1 = sXp[1][XPAD+n], x2 = sXp[2][XPAD+n], x3 = sXp[3][XPAD+n];
      f2 a0 = -sXp[NS+0][XPAD+n];
      a0 += cmul(sJ[0][0], x0); a0 += cmul(sJ[0][1], x1);
      a0 += cmul(sJ[0][2], x2); a0 += cmul(sJ[0][3], x3);
      f2 a1 = -sXp[NS+1][XPAD+n];
      a1 += cmul(sJ[1][0], x0); a1 += cmul(sJ[1][1], x1);
      a1 += cmul(sJ[1][2], x2); a1 += cmul(sJ[1][3], x3);
      sZ[0][n] = a0; sZ[1][n] = a1;
    }
    {
      const int bs = b*NS + wv;
#pragma unroll
      for (int i = 0; i < 8; ++i) {
        int n = lane + 64*i;
        yreg[i] = sXp[wv][XPAD+n];     // zero beyond NFR via pad
        wreg[i] = (n < NFR) ? wg[bs*NFR + n] : 0.f;
      }
    }
    __syncthreads();   // sZ ready
  } else {
    // ---- stage Z (zero-padded tail)
    for (int k = 0; k < NBK; ++k) {
      const size_t zb = ((size_t)(b*NBK + k)*NFQ + f)*NFR;
      for (int n = tid; n < NP; n += 256) sZ[k][n] = (n < NFR) ? Zg[zb+n] : mk2(0.f,0.f);
    }
    // ---- Y + w into registers
    {
      const size_t yb = ((size_t)(b*NS + wv)*NFQ + f)*NFR;
      const int bs = b*NS + wv;
#pragma unroll
      for (int i = 0; i < 8; ++i) {
        int n = lane + 64*i;
        if (n < NFR) { yreg[i] = Yg[yb+n]; wreg[i] = wg[bs*NFR + n]; }
        else         { yreg[i] = mk2(0.f,0.f); wreg[i] = 0.f; }
      }
    }
    if (tid < NS*NC) sW[tid/NC][tid%NC] = Wg[((size_t)(b*NS + tid/NC)*NFQ + f)*NC + tid%NC];
    else if (tid < NS*NC + NBK*NS) { int t=tid-NS*NC; sJ[t/NS][t%NS] = Jg[((size_t)(b*NBK+t/NS)*NFQ+f)*NS + t%NS]; }
    else if (tid < NS*NC + NBK*NS + NS*NS) { int t=tid-NS*NC-NBK*NS; sA[t/NS][t%NS] = Ag[((size_t)(b*NS+t/NS)*NFQ+f)*NS + t%NS]; }
    __syncthreads();
  }

  // bak-round v: SIX NAMED registers (never a runtime-indexed array -> no scratch)
  f2 vl0 = mk2(0.f,0.f), vl1 = mk2(0.f,0.f), vl2 = mk2(0.f,0.f);
  f2 vl3 = mk2(0.f,0.f), vl4 = mk2(0.f,0.f), vl5 = mk2(0.f,0.f);
#define V2T(t) (vl##t + cmul(sW[t][NS+0], vl4) + cmul(sW[t][NS+1], vl5))

  // ================= bak loop (4 barriers/round) =================
  for (int bak = 0; bak < NBK; ++bak) {
    // --- phase S: fold in previous round's A-update (P2); zs computed inline
    if (bak > 0 && tid < 16) {
      int s = tid >> 2, c = tid & 3;
      f2 v20 = V2T(0), v21 = V2T(1), v22 = V2T(2), v23 = V2T(3);
      f2 den = mk2(1.f,0.f);
      den -= cmul(v20, sgA[0]); den -= cmul(v21, sgA[1]);
      den -= cmul(v22, sgA[2]); den -= cmul(v23, sgA[3]);
      float m2 = cmag2(den) + EPSF;
      f2 mul = mk2(den.x/m2, -den.y/m2);
      sA[s][c] += cmul(sAv[s], cmul(sgA[c], mul));
    }
    __syncthreads();

    // --- phase R: p,d reductions + g + sgo capture
    f2 zs[8];
    {
      f2 pr2 = mk2(0.f,0.f), pi2 = mk2(0.f,0.f), dd2 = mk2(0.f,0.f);
#pragma unroll
      for (int i = 0; i < 8; ++i) {
        int n = lane+64*i;
        zs[i] = sZ[bak][n] + sXp[NS+bak][XPAD+n];
        f2 wy = wreg[i]*yreg[i];
        pr2 += wy * zs[i];
        pi2 += wy.yx * mk2(zs[i].x, -zs[i].y);
        dd2 += (wreg[i]*zs[i]) * zs[i];
      }
      float pr = wred64(pr2.x+pr2.y), pi = wred64(pi2.x+pi2.y), dd = wred64(dd2.x+dd2.y);
      if (lane == 0) { sp[wv] = mk2(pr*(1.f/NFR), pi*(1.f/NFR)); sd[wv] = dd*(1.f/NFR); }
      if (wv < NBK) {   // channels 4,5 (unweighted, rows = Z)
        f2 qr2 = mk2(0.f,0.f), qi2 = mk2(0.f,0.f), qd2 = mk2(0.f,0.f);
#pragma unroll
        for (int i = 0; i < 8; ++i) {
          f2 y = sZ[wv][lane+64*i];
          qr2 += y * zs[i];
          qi2 += y.yx * mk2(zs[i].x, -zs[i].y);
          qd2 += zs[i]*zs[i];
        }
        float qr = wred64(qr2.x+qr2.y), qi = wred64(qi2.x+qi2.y), qd = wred64(qd2.x+qd2.y);
        if (lane == 0) { sp[NS+wv] = mk2(qr*(1.f/NFR), qi*(1.f/NFR)); sd[NS+wv] = qd*(1.f/NFR); }
      }
    }
    if (tid < NC) {   // g[c] = conj( sum_s J[bak][s] * A2[s][c] )
      int c = tid; f2 acc = mk2(0.f,0.f);
      for (int s = 0; s < NS; ++s) {
        f2 a2;
        if (c < NS) a2 = sA[s][c];
        else {
          a2 = mk2(0.f,0.f);
          for (int k = 0; k < NS; ++k) a2 += cmul(sA[s][k], sW[k][c]);
        }
        acc += cmul(sJ[bak][s], a2);
      }
      sg[c] = conjc(acc);
    } else if (tid >= 8 && tid < 8+NS) {
      sgo[tid-8] = sJ[bak][tid-8];    // snapshot old J[bak]
    }
    __syncthreads();

    // --- phase U: every thread computes ell + v into NAMED regs; Y/Z updates
    {
      float gdg = 0.f; f2 gdp = mk2(0.f,0.f);
#pragma unroll
      for (int c = 0; c < NC; ++c) {
        f2 gc = sg[c]; float id = 1.0f/(sd[c] + EPSF);
        gdg += cmag2(gc) * id;
        gdp += id * cmulc(sp[c], gc);
      }
      f2 bb = mk2(1.0f - gdp.x, -gdp.y);
      float b1 = cmag2(bb);
      float a = b1*gdg + TINYF;
      float beta = (-b1 + sqrtf(b1*b1 + 4.0f*a)) / (2.0f*a);
      f2 ell = (b1 > EPSF*EPSF) ? (beta*bb) : mk2(1.0f/sqrtf(EPSF + gdg), 0.f);
#define CALCV(c) ((1.0f/(sd[c] + EPSF)) * (sp[c] - cmul(ell, sg[c])))
      vl0 = CALCV(0); vl1 = CALCV(1); vl2 = CALCV(2);
      vl3 = CALCV(3); vl4 = CALCV(4); vl5 = CALCV(5);
#undef CALCV
    }
    {
      // wave-uniform selects (cndmask): no register-array indexing
      f2 vc  = (wv == 0) ? vl0 : (wv == 1) ? vl1 : (wv == 2) ? vl2 : vl3;
#pragma unroll
      for (int i = 0; i < 8; ++i) yreg[i] -= cmul(vc, zs[i]);
      if (wv < NBK) {
        f2 v2c = (wv == 0) ? vl4 : vl5;
#pragma unroll
        for (int i = 0; i < 8; ++i) sZ[wv][lane+64*i] -= cmul(v2c, zs[i]);
      }
    }
    __syncthreads();

    // --- phase P1: Av, gA, W/J rank-1 updates (disjoint threads, named v regs)
    if (tid < NS) {
      f2 v20 = V2T(0), v21 = V2T(1), v22 = V2T(2), v23 = V2T(3);
      f2 acc = cmul(sA[tid][0], v20);
      acc += cmul(sA[tid][1], v21);
      acc += cmul(sA[tid][2], v22);
      acc += cmul(sA[tid][3], v23);
      sAv[tid] = acc;
    } else if (tid < 2*NS) {
      int c = tid - NS; f2 acc = mk2(0.f,0.f);
#pragma unroll
      for (int s = 0; s < NS; ++s) acc += cmul(sgo[s], sA[s][c]);
      sgA[c] = acc;
    } else if (tid < 2*NS + 16) {
      int idx = tid - 2*NS; int cc = idx >> 2, d = idx & 3;
      f2 vcc = (cc == 0) ? vl0 : (cc == 1) ? vl1 : (cc == 2) ? vl2 : vl3;
      sW[cc][d] -= cmul(vcc, sgo[d]);
    } else if (tid < 2*NS + 16 + 8) {
      int idx = tid - 2*NS - 16; int k = idx >> 2, d = idx & 3;
      f2 vk = (k == 0) ? vl4 : vl5;
      sJ[k][d] -= cmul(vk, sgo[d]);
    }
    __syncthreads();
  }

  // ================= type1 loop (4 rounds) + deferred mat_up1 ==============
  for (int src = 0; src < NS; ++src) {
    if (wv == src) {
#pragma unroll
      for (int i = 0; i < 8; ++i) sS[lane+64*i] = yreg[i];
    }
    if (tid < NC) sWsrc[tid] = sW[src][tid];
    if (src == 0) {
      if (tid < 16) {     // final P2 of bak loop (uses named v regs from bak=1)
        int s = tid >> 2, c = tid & 3;
        f2 v20 = V2T(0), v21 = V2T(1), v22 = V2T(2), v23 = V2T(3);
        f2 den = mk2(1.f,0.f);
        den -= cmul(v20, sgA[0]); den -= cmul(v21, sgA[1]);
        den -= cmul(v22, sgA[2]); den -= cmul(v23, sgA[3]);
        float m2 = cmag2(den) + EPSF;
        f2 mul = mk2(den.x/m2, -den.y/m2);
        sA[s][c] += cmul(sAv[s], cmul(sgA[c], mul));
      }
    } else if (tid >= 8 && tid < 8+NS) {   // mat_up1 for previous src
      int r = tid - 8, prev = src - 1;
      f2 acc = mk2(0.f,0.f);
#pragma unroll
      for (int c = 0; c < NS; ++c) acc += cmul(sA[r][c], sv[c]);
      float den = 1.0f - sv[prev].x + EPSF;
      sA[r][prev] += (1.0f/den) * acc;
    }
    __syncthreads();

    {
      f2 ys[8];
      f2 nr2 = mk2(0.f,0.f), ni2 = mk2(0.f,0.f), dd2 = mk2(0.f,0.f);
#pragma unroll
      for (int i = 0; i < 8; ++i) {
        ys[i] = sS[lane+64*i];
        f2 wy = wreg[i]*yreg[i];
        nr2 += wy * ys[i];
        ni2 += wy.yx * mk2(ys[i].x, -ys[i].y);
        dd2 += (wreg[i]*ys[i]) * ys[i];
      }
      float nr = wred64(nr2.x+nr2.y)*(1.f/NFR);
      float ni = wred64(ni2.x+ni2.y)*(1.f/NFR);
      float dd = wred64(dd2.x+dd2.y)*(1.f/NFR);
      f2 vc;
      if (wv == src) vc = mk2(1.0f - 1.0f/sqrtf(fmaxf(dd, EPSF)), 0.f);
      else           vc = (1.0f/fmaxf(dd, EPSF)) * mk2(nr, ni);
      if (lane == 0) sv[wv] = vc;
#pragma unroll
      for (int i = 0; i < 8; ++i) yreg[i] -= cmul(vc, ys[i]);
      if (lane < NC) sW[wv][lane] -= cmul(vc, sWsrc[lane]);
    }
    __syncthreads();
  }
  // (mat_up1 for src=3 is dead: A is overwritten by the Binv inverse below)

  // ================= type2: pair-batched (barrier-free, Z rows fixed) ======
  {
    f2 pr0=mk2(0,0), pi0=mk2(0,0), dd0=mk2(0,0);
    f2 pr1=mk2(0,0), pi1=mk2(0,0), dd1=mk2(0,0);
    f2 crr=mk2(0,0), cri=mk2(0,0);
    f2 z0c[8], z1c[8];
#pragma unroll
    for (int i = 0; i < 8; ++i) {
      f2 z0 = sZ[0][lane+64*i], z1 = sZ[1][lane+64*i];
      z0c[i] = z0; z1c[i] = z1;
      f2 wy = wreg[i]*yreg[i];
      f2 wz0 = wreg[i]*z0;
      pr0 += wy * z0;  pi0 += wy.yx * mk2(z0.x, -z0.y);  dd0 += wz0 * z0;
      pr1 += wy * z1;  pi1 += wy.yx * mk2(z1.x, -z1.y);  dd1 += (wreg[i]*z1) * z1;
      crr += wz0 * z1; cri += wz0.yx * mk2(z1.x, -z1.y);   // Rz = sum w z0 conj(z1)
    }
    float P0r = wred64(pr0.x+pr0.y), P0i = wred64(pi0.x+pi0.y), D0 = wred64(dd0.x+dd0.y);
    float P1r = wred64(pr1.x+pr1.y), P1i = wred64(pi1.x+pi1.y), D1 = wred64(dd1.x+dd1.y);
    float Rr  = wred64(crr.x+crr.y), Ri  = wred64(cri.x+cri.y);
    f2 v0 = (1.0f/fmaxf(D0, EPSF)) * mk2(P0r, P0i);
    f2 P1c = mk2(P1r, P1i) - cmul(v0, mk2(Rr, Ri));
    f2 v1 = (1.0f/fmaxf(D1, EPSF)) * P1c;
#pragma unroll
    for (int i = 0; i < 8; ++i) yreg[i] -= cmul(v0, z0c[i]) + cmul(v1, z1c[i]);
    if (lane < NS) sW[wv][lane] -= cmul(v0, sJ[0][lane]) + cmul(v1, sJ[1][lane]);
    else if (lane == NS)   sW[wv][NS+0] += v0;
    else if (lane == NS+1) sW[wv][NS+1] += v1;
  }
  __syncthreads();

  // ================= Binv -> inv (GJ on tid 0, LDS-resident; overlaps type3)
  if (!last) {
    if (tid < 16) {
      int s = tid >> 2, d = tid & 3;
      f2 acc = sW[s][d];
      acc += cmul(sW[s][NS+0], sJ[0][d]);
      acc += cmul(sW[s][NS+1], sJ[1][d]);
      sB[s][d] = acc;
      sB[s][NS+d] = (s==d) ? mk2(1.f,0.f) : mk2(0.f,0.f);
    }
    __syncthreads();
    if (tid == 0) {
      for (int col = 0; col < NS; ++col) {
        int piv = col; float best = cmag2(sB[col][col]);
        for (int r = col+1; r < NS; ++r) { float m = cmag2(sB[r][col]); if (m > best) { best = m; piv = r; } }
        if (piv != col) for (int k = 0; k < 2*NS; ++k) { f2 t = sB[col][k]; sB[col][k] = sB[piv][k]; sB[piv][k] = t; }
        f2 ip = cinv(sB[col][col]);
        for (int k = 0; k < 2*NS; ++k) sB[col][k] = cmul(sB[col][k], ip);
        for (int r = 0; r < NS; ++r) if (r != col) {
          f2 fac = sB[r][col];
          for (int k = 0; k < 2*NS; ++k) sB[r][k] -= cmul(fac, sB[col][k]);
        }
      }
    }
  }

  // ================= type3: sequential rounds (barrier-free; regs Y/w) =====
  {
#pragma unroll 1
    for (int src = 0; src < NC; ++src) {
      const f2* __restrict__ xrow = &sXp[src][0];
#pragma unroll
      for (int tap = 0; tap < NT; ++tap) {
        const int xoff = XPAD - (NDLY + tap) + lane;
        f2 xs[8];
        f2 nr2 = mk2(0.f,0.f), ni2 = mk2(0.f,0.f), dd2 = mk2(0.f,0.f);
#pragma unroll
        for (int i = 0; i < 8; ++i) {
          xs[i] = xrow[xoff + 64*i];
          f2 wy = wreg[i]*yreg[i];
          nr2 += wy * xs[i];
          ni2 += wy.yx * mk2(xs[i].x, -xs[i].y);
          dd2 += (wreg[i]*xs[i]) * xs[i];
        }
        float nr = wred64(nr2.x+nr2.y), ni = wred64(ni2.x+ni2.y), dd = wred64(dd2.x+dd2.y);
        f2 vc = (1.0f/fmaxf(dd, EPSF)) * mk2(nr, ni);
#pragma unroll
        for (int i = 0; i < 8; ++i) yreg[i] -= cmul(vc, xs[i]);
      }
    }
  }

  // ================= epilogue =================
  {
    const size_t yb = ((size_t)(b*NS + wv)*NFQ + f)*NFR;
    if (last) {
#pragma unroll
      for (int i = 0; i < 8; ++i) { int n = lane+64*i; if (n < NFR) outR[yb+n] = yreg[i].x; }
    } else {
#pragma unroll
      for (int i = 0; i < 8; ++i) { int n = lane+64*i; if (n < NFR) Yg[yb+n] = yreg[i]; }
    }
  }
  if (!last) {
    __syncthreads();   // sB (GJ), sW/sJ cross-wave reads below
    for (int k = 0; k < NBK; ++k) {
      const size_t zb = ((size_t)(b*NBK+k)*NFQ + f)*NFR;
      for (int n = tid; n < NFR; n += 256) Zg[zb+n] = sZ[k][n];
    }
    if (tid < NS*NC) Wg[((size_t)(b*NS + tid/NC)*NFQ + f)*NC + tid%NC] = sW[tid/NC][tid%NC];
    else if (tid < NS*NC + NBK*NS) { int t = tid - NS*NC; Jg[((size_t)(b*NBK + t/NS)*NFQ + f)*NS + t%NS] = sJ[t/NS][t%NS]; }
    else if (tid < NS*NC + NBK*NS + NS*NS) { int t = tid - NS*NC - NBK*NS; Ag[((size_t)(b*NS + t/NS)*NFQ + f)*NS + t%NS] = sB[t/NS][NS + t%NS]; }
  }
#undef V2T
}

// ---------------------------------------------------------------------------
extern "C" void kernel_launch(void* const* d_in, const int* in_sizes, int n_in,
                              void* d_out, int out_size, void* d_ws, size_t ws_size,
                              hipStream_t stream)
{
  (void)in_sizes; (void)n_in; (void)out_size; (void)ws_size;
  const float* Xr = (const float*)d_in[0];
  const float* Xi = (const float*)d_in[1];
  float* outR = (float*)d_out;   // d_out = re(Y), float32, (2,4,320,500)

  char* ws = (char*)d_ws;
  size_t off = 0;
  f2* Yg = (f2*)(ws + off); off += (size_t)NB*NS*NFQ*NFR*sizeof(f2);   // 10,240,000
  f2* Zg = (f2*)(ws + off); off += (size_t)NB*NBK*NFQ*NFR*sizeof(f2);  //  5,120,000
  f2* Wg = (f2*)(ws + off); off += (size_t)NB*NS*NFQ*NC*sizeof(f2);    //    122,880
  f2* Jg = (f2*)(ws + off); off += (size_t)NB*NBK*NFQ*NS*sizeof(f2);   //     40,960
  f2* Ag = (f2*)(ws + off); off += (size_t)NB*NS*NFQ*NS*sizeof(f2);    //     81,920
  float* wg = (float*)(ws + off); off += (size_t)NB*NS*NFR*sizeof(float); //  16,000

  // iter 0 (init folded in): final w from X, then fused init+iss
  k_wX<<<NB*NS, 512, 0, stream>>>(Xr, Xi, wg);
  k_iter<<<NB*NFQ, 256, 0, stream>>>(Xr, Xi, Yg, Zg, Wg, Jg, Ag, wg, outR, 1, 0);
  // iter 1 (last): final w from Y, then iss, write re(Y) to out
  k_wY<<<NB*NS, 512, 0, stream>>>(Yg, wg);
  k_iter<<<NB*NFQ, 256, 0, stream>>>(Xr, Xi, Yg, Zg, Wg, Jg, Ag, wg, outR, 0, 1);
}

// Round 11
// 113.634 us; speedup vs baseline: 1.2027x; 1.2027x over previous
//
#include <hip/hip_runtime.h>

#define NFR 500   // n_frames
#define NFQ 320   // n_freq
#define NB  2     // batch
#define NC  6     // n_chan
#define NS  4     // n_src
#define NBK 2     // n_chan - n_src
#define NT  4     // n_taps
#define NDLY 1    // n_delay
#define EPSF 1e-3f
#define TINYF 1e-20f

#define NP   512            // padded frame count (8 x 64 lanes)
#define XPAD 8              // leading zero-pad for shifted X reads
#define XLEN (XPAD + NP)
#define NCH  8              // f-chunks for w partial sums
#define FPC  (NFQ / NCH)    // 40 freqs per chunk

typedef float f2 __attribute__((ext_vector_type(2)));

__device__ __forceinline__ f2 mk2(float r, float i){ f2 t; t.x = r; t.y = i; return t; }
// complex ops on (re,im) pairs — select v_pk_* packed fp32
__device__ __forceinline__ f2 cmul(f2 a, f2 b){ return a.xx*b + a.yy*mk2(-b.y, b.x); }
__device__ __forceinline__ f2 cmulc(f2 a, f2 b){ return b.xx*a + b.yy*mk2(a.y, -a.x); } // a*conj(b)
__device__ __forceinline__ f2 conjc(f2 a){ return mk2(a.x, -a.y); }
__device__ __forceinline__ float cmag2(f2 a){ return a.x*a.x + a.y*a.y; }
__device__ __forceinline__ f2 cinv(f2 a){ float m = a.x*a.x + a.y*a.y; return mk2(a.x/m, -a.y/m); }

// wave64 sum-reduce via DPP (VALU latency); result uniform via readlane(63)
#define DPPF(x, ctrl) __int_as_float(__builtin_amdgcn_mov_dpp(__float_as_int(x), (ctrl), 0xF, 0xF, true))
__device__ __forceinline__ float wred64(float x){
  x += DPPF(x, 0x111);   // row_shr:1
  x += DPPF(x, 0x112);   // row_shr:2
  x += DPPF(x, 0x114);   // row_shr:4
  x += DPPF(x, 0x118);   // row_shr:8
  x += DPPF(x, 0x142);   // row_bcast:15
  x += DPPF(x, 0x143);   // row_bcast:31
  return __int_as_float(__builtin_amdgcn_readlane(__float_as_int(x), 63));
}

// ---------------------------------------------------------------------------
// w partials from X (iteration 0: Y == X[:4]); 64 blocks = 8 chunks x 8 (b,s)
// ---------------------------------------------------------------------------
__global__ __launch_bounds__(512) void k_wpartX(const float* __restrict__ Xr,
                                                const float* __restrict__ Xi,
                                                float* __restrict__ wacc)
{
  const int bs = blockIdx.x / NCH;       // b*NS + s
  const int ch = blockIdx.x % NCH;
  const int n  = threadIdx.x;
  if (n >= NFR) return;
  const int b = bs / NS, s = bs % NS;
  const size_t rowb = ((size_t)(b*NC + s)*NFQ)*NFR + n;
  float acc = 0.f;
  for (int ff = 0; ff < FPC; ++ff) {
    size_t idx = rowb + (size_t)(ch*FPC + ff)*NFR;
    float xr = Xr[idx], xi = Xi[idx];
    acc += xr*xr + xi*xi;
  }
  wacc[((size_t)(ch*NB*NS + bs))*NFR + n] = acc;
}

// ---------------------------------------------------------------------------
// w partials from Y (between iterations); 64 blocks
// ---------------------------------------------------------------------------
__global__ __launch_bounds__(512) void k_wpartY(const f2* __restrict__ Yg,
                                                float* __restrict__ wacc)
{
  const int bs = blockIdx.x / NCH;
  const int ch = blockIdx.x % NCH;
  const int n  = threadIdx.x;
  if (n >= NFR) return;
  const f2* row = Yg + (size_t)bs*NFQ*NFR + n;
  f2 acc2 = mk2(0.f,0.f);
  for (int ff = 0; ff < FPC; ++ff)
    { f2 y = row[(size_t)(ch*FPC + ff)*NFR]; acc2 += y*y; }
  wacc[((size_t)(ch*NB*NS + bs))*NFR + n] = acc2.x + acc2.y;
}

// ---------------------------------------------------------------------------
// finalize w: wg[bs][n] = 1/max(mean, eps); 8 blocks, L2-resident reads
// ---------------------------------------------------------------------------
__global__ __launch_bounds__(512) void k_wfin(const float* __restrict__ wacc,
                                              float* __restrict__ wg)
{
  const int bs = blockIdx.x;
  const int n  = threadIdx.x;
  if (n >= NFR) return;
  float a = 0.f;
#pragma unroll
  for (int ch = 0; ch < NCH; ++ch) a += wacc[((size_t)(ch*NB*NS + bs))*NFR + n];
  wg[bs*NFR + n] = 1.0f / fmaxf(a * (1.0f/(float)NFQ), EPSF);
}

// ---------------------------------------------------------------------------
// one full iss_updates iteration per (b,f) block. Y,w in registers (wave-owned
// channel); X zero-padded in LDS; packed-fp32 math; DPP reductions; H dead.
// Scratch-free: bak-round v in six NAMED registers; init GJ in-place on LDS.
// ---------------------------------------------------------------------------
__global__ __launch_bounds__(256, 3) void k_iter(
  const float* __restrict__ Xr, const float* __restrict__ Xi,
  f2* __restrict__ Yg, f2* __restrict__ Zg,
  f2* __restrict__ Wg, f2* __restrict__ Jg, f2* __restrict__ Ag,
  const float* __restrict__ wg, float* __restrict__ outR,
  const int first, const int last)
{
  __shared__ f2 sXp[NC][XLEN];   // front/back zero-padded X
  __shared__ f2 sZ[NBK][NP];
  __shared__ f2 sS[NP];
  __shared__ f2 sW[NS][NC];
  __shared__ f2 sJ[NBK][NS];
  __shared__ f2 sA[NS][NS];
  __shared__ f2 sB[NS][2*NS];    // GJ scratch (LDS); also C_XX staging when first
  __shared__ f2 sv[NC], sg[NC], sgo[NS];
  __shared__ float sd[NC];
  __shared__ f2 sp[NC];
  __shared__ f2 sAv[NS], sgA[NS], sWsrc[NC];

  const int bf = blockIdx.x;
  const int b = bf / NFQ, f = bf % NFQ;
  const int tid = threadIdx.x, wv = tid >> 6, lane = tid & 63;

  f2 yreg[8];   // wave-owned channel wv
  float wreg[8];

  // ---- stage X (zero-padded both ends)
  for (int c = 0; c < NC; ++c) {
    const size_t base = ((size_t)(b*NC + c)*NFQ + f)*NFR;
    for (int j = tid; j < XLEN; j += 256) {
      int n = j - XPAD;
      sXp[c][j] = (n >= 0 && n < NFR) ? mk2(Xr[base+n], Xi[base+n]) : mk2(0.f,0.f);
    }
  }

  if (first) {
    __syncthreads();   // X staged
    // ---- C_XX[s][d] partials into sB (s<4, d<6); W/A = eye
    for (int p = wv; p < NS*NC; p += 4) {
      int s = p / NC, d = p % NC;
      f2 ar2 = mk2(0.f,0.f), ai2 = mk2(0.f,0.f);
#pragma unroll
      for (int i = 0; i < 8; ++i) {
        int n = lane + 64*i;                     // padded zeros harmless
        f2 xs = sXp[s][XPAD+n], xd = sXp[d][XPAD+n];
        ar2 += xs * xd;
        ai2 += xs.yx * mk2(xd.x, -xd.y);
      }
      float ar = wred64(ar2.x + ar2.y), ai = wred64(ai2.x + ai2.y);
      if (lane == 0) sB[s][d] = mk2(ar*(1.f/NFR), ai*(1.f/NFR));
    }
    if (tid >= 192 && tid < 192 + NS*NC) {
      int t = tid - 192; sW[t/NC][t%NC] = (t/NC == t%NC) ? mk2(1.f,0.f) : mk2(0.f,0.f);
    } else if (tid >= 224 && tid < 224 + NS*NS) {
      int t = tid - 224; sA[t/NS][t%NS] = (t/NS == t%NS) ? mk2(1.f,0.f) : mk2(0.f,0.f);
    }
    __syncthreads();
    if (tid == 0) {   // diag-loaded GJ solve IN-PLACE on LDS sB -> J
      float dsum = 0.f;
      for (int s = 0; s < NS; ++s) dsum += sqrtf(cmag2(sB[s][s]));
      float load = fmaxf(dsum*1e-5f, 1e-5f);
      for (int s = 0; s < NS; ++s) sB[s][s].x += load;
      for (int col = 0; col < NS; ++col) {
        int piv = col; float best = cmag2(sB[col][col]);
        for (int r = col+1; r < NS; ++r) { float m = cmag2(sB[r][col]); if (m > best){best=m; piv=r;} }
        if (piv != col) for (int k = col; k < NC; ++k) { f2 t=sB[col][k]; sB[col][k]=sB[piv][k]; sB[piv][k]=t; }
        f2 ip = cinv(sB[col][col]);
        for (int k = col; k < NC; ++k) sB[col][k] = cmul(sB[col][k], ip);
        for (int r = 0; r < NS; ++r) if (r != col) {
          f2 fac = sB[r][col];
          for (int k = col; k < NC; ++k) sB[r][k] -= cmul(fac, sB[col][k]);
        }
      }
      for (int k = 0; k < NBK; ++k)
        for (int s = 0; s < NS; ++s) sJ[k][s] = conjc(sB[s][NS+k]);
    }
    __syncthreads();   // sJ ready
    // ---- Z = J X - X[4:] (LDS), Y = X[:4] (regs), w from wg
    for (int n = tid; n < NP; n += 256) {
      f2 x0 = sXp[0][XPAD+n], x1 = sXp[1][XPAD+n], x2 = sXp[2][XPAD+n], x3 = sXp[3][XPAD+n];
      f2 a0 = -sXp[NS+0][XPAD+n];
      a0 += cmul(sJ[0][0], x0); a0 += cmul(sJ[0][1], x1);
      a0 += cmul(sJ[0][2], x2); a0 += cmul(sJ[0][3], x3);
      f2 a1 = -sXp[NS+1][XPAD+n];
      a1 += cmul(sJ[1][0], x0); a1 += cmul(sJ[1][1], x1);
      a1 += cmul(sJ[1][2], x2); a1 += cmul(sJ[1][3], x3);
      sZ[0][n] = a0; sZ[1][n] = a1;
    }
    {
      const int bs = b*NS + wv;
#pragma unroll
      for (int i = 0; i < 8; ++i) {
        int n = lane + 64*i;
        yreg[i] = sXp[wv][XPAD+n];     // zero beyond NFR via pad
        wreg[i] = (n < NFR) ? wg[bs*NFR + n] : 0.f;
      }
    }
    __syncthreads();   // sZ ready
  } else {
    // ---- stage Z (zero-padded tail)
    for (int k = 0; k < NBK; ++k) {
      const size_t zb = ((size_t)(b*NBK + k)*NFQ + f)*NFR;
      for (int n = tid; n < NP; n += 256) sZ[k][n] = (n < NFR) ? Zg[zb+n] : mk2(0.f,0.f);
    }
    // ---- Y + w into registers
    {
      const size_t yb = ((size_t)(b*NS + wv)*NFQ + f)*NFR;
      const int bs = b*NS + wv;
#pragma unroll
      for (int i = 0; i < 8; ++i) {
        int n = lane + 64*i;
        if (n < NFR) { yreg[i] = Yg[yb+n]; wreg[i] = wg[bs*NFR + n]; }
        else         { yreg[i] = mk2(0.f,0.f); wreg[i] = 0.f; }
      }
    }
    if (tid < NS*NC) sW[tid/NC][tid%NC] = Wg[((size_t)(b*NS + tid/NC)*NFQ + f)*NC + tid%NC];
    else if (tid < NS*NC + NBK*NS) { int t=tid-NS*NC; sJ[t/NS][t%NS] = Jg[((size_t)(b*NBK+t/NS)*NFQ+f)*NS + t%NS]; }
    else if (tid < NS*NC + NBK*NS + NS*NS) { int t=tid-NS*NC-NBK*NS; sA[t/NS][t%NS] = Ag[((size_t)(b*NS+t/NS)*NFQ+f)*NS + t%NS]; }
    __syncthreads();
  }

  // bak-round v: SIX NAMED registers (never a runtime-indexed array -> no scratch)
  f2 vl0 = mk2(0.f,0.f), vl1 = mk2(0.f,0.f), vl2 = mk2(0.f,0.f);
  f2 vl3 = mk2(0.f,0.f), vl4 = mk2(0.f,0.f), vl5 = mk2(0.f,0.f);
#define V2T(t) (vl##t + cmul(sW[t][NS+0], vl4) + cmul(sW[t][NS+1], vl5))

  // ================= bak loop (4 barriers/round) =================
  for (int bak = 0; bak < NBK; ++bak) {
    // --- phase S: fold in previous round's A-update (P2); zs computed inline
    if (bak > 0 && tid < 16) {
      int s = tid >> 2, c = tid & 3;
      f2 v20 = V2T(0), v21 = V2T(1), v22 = V2T(2), v23 = V2T(3);
      f2 den = mk2(1.f,0.f);
      den -= cmul(v20, sgA[0]); den -= cmul(v21, sgA[1]);
      den -= cmul(v22, sgA[2]); den -= cmul(v23, sgA[3]);
      float m2 = cmag2(den) + EPSF;
      f2 mul = mk2(den.x/m2, -den.y/m2);
      sA[s][c] += cmul(sAv[s], cmul(sgA[c], mul));
    }
    __syncthreads();

    // --- phase R: p,d reductions + g + sgo capture
    f2 zs[8];
    {
      f2 pr2 = mk2(0.f,0.f), pi2 = mk2(0.f,0.f), dd2 = mk2(0.f,0.f);
#pragma unroll
      for (int i = 0; i < 8; ++i) {
        int n = lane+64*i;
        zs[i] = sZ[bak][n] + sXp[NS+bak][XPAD+n];
        f2 wy = wreg[i]*yreg[i];
        pr2 += wy * zs[i];
        pi2 += wy.yx * mk2(zs[i].x, -zs[i].y);
        dd2 += (wreg[i]*zs[i]) * zs[i];
      }
      float pr = wred64(pr2.x+pr2.y), pi = wred64(pi2.x+pi2.y), dd = wred64(dd2.x+dd2.y);
      if (lane == 0) { sp[wv] = mk2(pr*(1.f/NFR), pi*(1.f/NFR)); sd[wv] = dd*(1.f/NFR); }
      if (wv < NBK) {   // channels 4,5 (unweighted, rows = Z)
        f2 qr2 = mk2(0.f,0.f), qi2 = mk2(0.f,0.f), qd2 = mk2(0.f,0.f);
#pragma unroll
        for (int i = 0; i < 8; ++i) {
          f2 y = sZ[wv][lane+64*i];
          qr2 += y * zs[i];
          qi2 += y.yx * mk2(zs[i].x, -zs[i].y);
          qd2 += zs[i]*zs[i];
        }
        float qr = wred64(qr2.x+qr2.y), qi = wred64(qi2.x+qi2.y), qd = wred64(qd2.x+qd2.y);
        if (lane == 0) { sp[NS+wv] = mk2(qr*(1.f/NFR), qi*(1.f/NFR)); sd[NS+wv] = qd*(1.f/NFR); }
      }
    }
    if (tid < NC) {   // g[c] = conj( sum_s J[bak][s] * A2[s][c] )
      int c = tid; f2 acc = mk2(0.f,0.f);
      for (int s = 0; s < NS; ++s) {
        f2 a2;
        if (c < NS) a2 = sA[s][c];
        else {
          a2 = mk2(0.f,0.f);
          for (int k = 0; k < NS; ++k) a2 += cmul(sA[s][k], sW[k][c]);
        }
        acc += cmul(sJ[bak][s], a2);
      }
      sg[c] = conjc(acc);
    } else if (tid >= 8 && tid < 8+NS) {
      sgo[tid-8] = sJ[bak][tid-8];    // snapshot old J[bak]
    }
    __syncthreads();

    // --- phase U: every thread computes ell + v into NAMED regs; Y/Z updates
    {
      float gdg = 0.f; f2 gdp = mk2(0.f,0.f);
#pragma unroll
      for (int c = 0; c < NC; ++c) {
        f2 gc = sg[c]; float id = 1.0f/(sd[c] + EPSF);
        gdg += cmag2(gc) * id;
        gdp += id * cmulc(sp[c], gc);
      }
      f2 bb = mk2(1.0f - gdp.x, -gdp.y);
      float b1 = cmag2(bb);
      float a = b1*gdg + TINYF;
      float beta = (-b1 + sqrtf(b1*b1 + 4.0f*a)) / (2.0f*a);
      f2 ell = (b1 > EPSF*EPSF) ? (beta*bb) : mk2(1.0f/sqrtf(EPSF + gdg), 0.f);
#define CALCV(c) ((1.0f/(sd[c] + EPSF)) * (sp[c] - cmul(ell, sg[c])))
      vl0 = CALCV(0); vl1 = CALCV(1); vl2 = CALCV(2);
      vl3 = CALCV(3); vl4 = CALCV(4); vl5 = CALCV(5);
#undef CALCV
    }
    {
      // wave-uniform selects (cndmask): no register-array indexing
      f2 vc  = (wv == 0) ? vl0 : (wv == 1) ? vl1 : (wv == 2) ? vl2 : vl3;
#pragma unroll
      for (int i = 0; i < 8; ++i) yreg[i] -= cmul(vc, zs[i]);
      if (wv < NBK) {
        f2 v2c = (wv == 0) ? vl4 : vl5;
#pragma unroll
        for (int i = 0; i < 8; ++i) sZ[wv][lane+64*i] -= cmul(v2c, zs[i]);
      }
    }
    __syncthreads();

    // --- phase P1: Av, gA, W/J rank-1 updates (disjoint threads, named v regs)
    if (tid < NS) {
      f2 v20 = V2T(0), v21 = V2T(1), v22 = V2T(2), v23 = V2T(3);
      f2 acc = cmul(sA[tid][0], v20);
      acc += cmul(sA[tid][1], v21);
      acc += cmul(sA[tid][2], v22);
      acc += cmul(sA[tid][3], v23);
      sAv[tid] = acc;
    } else if (tid < 2*NS) {
      int c = tid - NS; f2 acc = mk2(0.f,0.f);
#pragma unroll
      for (int s = 0; s < NS; ++s) acc += cmul(sgo[s], sA[s][c]);
      sgA[c] = acc;
    } else if (tid < 2*NS + 16) {
      int idx = tid - 2*NS; int cc = idx >> 2, d = idx & 3;
      f2 vcc = (cc == 0) ? vl0 : (cc == 1) ? vl1 : (cc == 2) ? vl2 : vl3;
      sW[cc][d] -= cmul(vcc, sgo[d]);
    } else if (tid < 2*NS + 16 + 8) {
      int idx = tid - 2*NS - 16; int k = idx >> 2, d = idx & 3;
      f2 vk = (k == 0) ? vl4 : vl5;
      sJ[k][d] -= cmul(vk, sgo[d]);
    }
    __syncthreads();
  }

  // ================= type1 loop (4 rounds) + deferred mat_up1 ==============
  for (int src = 0; src < NS; ++src) {
    if (wv == src) {
#pragma unroll
      for (int i = 0; i < 8; ++i) sS[lane+64*i] = yreg[i];
    }
    if (tid < NC) sWsrc[tid] = sW[src][tid];
    if (src == 0) {
      if (tid < 16) {     // final P2 of bak loop (uses named v regs from bak=1)
        int s = tid >> 2, c = tid & 3;
        f2 v20 = V2T(0), v21 = V2T(1), v22 = V2T(2), v23 = V2T(3);
        f2 den = mk2(1.f,0.f);
        den -= cmul(v20, sgA[0]); den -= cmul(v21, sgA[1]);
        den -= cmul(v22, sgA[2]); den -= cmul(v23, sgA[3]);
        float m2 = cmag2(den) + EPSF;
        f2 mul = mk2(den.x/m2, -den.y/m2);
        sA[s][c] += cmul(sAv[s], cmul(sgA[c], mul));
      }
    } else if (tid >= 8 && tid < 8+NS) {   // mat_up1 for previous src
      int r = tid - 8, prev = src - 1;
      f2 acc = mk2(0.f,0.f);
#pragma unroll
      for (int c = 0; c < NS; ++c) acc += cmul(sA[r][c], sv[c]);
      float den = 1.0f - sv[prev].x + EPSF;
      sA[r][prev] += (1.0f/den) * acc;
    }
    __syncthreads();

    {
      f2 ys[8];
      f2 nr2 = mk2(0.f,0.f), ni2 = mk2(0.f,0.f), dd2 = mk2(0.f,0.f);
#pragma unroll
      for (int i = 0; i < 8; ++i) {
        ys[i] = sS[lane+64*i];
        f2 wy = wreg[i]*yreg[i];
        nr2 += wy * ys[i];
        ni2 += wy.yx * mk2(ys[i].x, -ys[i].y);
        dd2 += (wreg[i]*ys[i]) * ys[i];
      }
      float nr = wred64(nr2.x+nr2.y)*(1.f/NFR);
      float ni = wred64(ni2.x+ni2.y)*(1.f/NFR);
      float dd = wred64(dd2.x+dd2.y)*(1.f/NFR);
      f2 vc;
      if (wv == src) vc = mk2(1.0f - 1.0f/sqrtf(fmaxf(dd, EPSF)), 0.f);
      else           vc = (1.0f/fmaxf(dd, EPSF)) * mk2(nr, ni);
      if (lane == 0) sv[wv] = vc;
#pragma unroll
      for (int i = 0; i < 8; ++i) yreg[i] -= cmul(vc, ys[i]);
      if (lane < NC) sW[wv][lane] -= cmul(vc, sWsrc[lane]);
    }
    __syncthreads();
  }
  // (mat_up1 for src=3 is dead: A is overwritten by the Binv inverse below)

  // ================= type2: pair-batched (barrier-free, Z rows fixed) ======
  {
    f2 pr0=mk2(0,0), pi0=mk2(0,0), dd0=mk2(0,0);
    f2 pr1=mk2(0,0), pi1=mk2(0,0), dd1=mk2(0,0);
    f2 crr=mk2(0,0), cri=mk2(0,0);
    f2 z0c[8], z1c[8];
#pragma unroll
    for (int i = 0; i < 8; ++i) {
      f2 z0 = sZ[0][lane+64*i], z1 = sZ[1][lane+64*i];
      z0c[i] = z0; z1c[i] = z1;
      f2 wy = wreg[i]*yreg[i];
      f2 wz0 = wreg[i]*z0;
      pr0 += wy * z0;  pi0 += wy.yx * mk2(z0.x, -z0.y);  dd0 += wz0 * z0;
      pr1 += wy * z1;  pi1 += wy.yx * mk2(z1.x, -z1.y);  dd1 += (wreg[i]*z1) * z1;
      crr += wz0 * z1; cri += wz0.yx * mk2(z1.x, -z1.y);   // Rz = sum w z0 conj(z1)
    }
    float P0r = wred64(pr0.x+pr0.y), P0i = wred64(pi0.x+pi0.y), D0 = wred64(dd0.x+dd0.y);
    float P1r = wred64(pr1.x+pr1.y), P1i = wred64(pi1.x+pi1.y), D1 = wred64(dd1.x+dd1.y);
    float Rr  = wred64(crr.x+crr.y), Ri  = wred64(cri.x+cri.y);
    f2 v0 = (1.0f/fmaxf(D0, EPSF)) * mk2(P0r, P0i);
    f2 P1c = mk2(P1r, P1i) - cmul(v0, mk2(Rr, Ri));
    f2 v1 = (1.0f/fmaxf(D1, EPSF)) * P1c;
#pragma unroll
    for (int i = 0; i < 8; ++i) yreg[i] -= cmul(v0, z0c[i]) + cmul(v1, z1c[i]);
    if (lane < NS) sW[wv][lane] -= cmul(v0, sJ[0][lane]) + cmul(v1, sJ[1][lane]);
    else if (lane == NS)   sW[wv][NS+0] += v0;
    else if (lane == NS+1) sW[wv][NS+1] += v1;
  }
  __syncthreads();

  // ================= Binv -> inv (GJ on tid 0, LDS-resident; overlaps type3)
  if (!last) {
    if (tid < 16) {
      int s = tid >> 2, d = tid & 3;
      f2 acc = sW[s][d];
      acc += cmul(sW[s][NS+0], sJ[0][d]);
      acc += cmul(sW[s][NS+1], sJ[1][d]);
      sB[s][d] = acc;
      sB[s][NS+d] = (s==d) ? mk2(1.f,0.f) : mk2(0.f,0.f);
    }
    __syncthreads();
    if (tid == 0) {
      for (int col = 0; col < NS; ++col) {
        int piv = col; float best = cmag2(sB[col][col]);
        for (int r = col+1; r < NS; ++r) { float m = cmag2(sB[r][col]); if (m > best) { best = m; piv = r; } }
        if (piv != col) for (int k = 0; k < 2*NS; ++k) { f2 t = sB[col][k]; sB[col][k] = sB[piv][k]; sB[piv][k] = t; }
        f2 ip = cinv(sB[col][col]);
        for (int k = 0; k < 2*NS; ++k) sB[col][k] = cmul(sB[col][k], ip);
        for (int r = 0; r < NS; ++r) if (r != col) {
          f2 fac = sB[r][col];
          for (int k = 0; k < 2*NS; ++k) sB[r][k] -= cmul(fac, sB[col][k]);
        }
      }
    }
  }

  // ================= type3: sequential rounds (barrier-free; regs Y/w) =====
  {
#pragma unroll 1
    for (int src = 0; src < NC; ++src) {
      const f2* __restrict__ xrow = &sXp[src][0];
#pragma unroll
      for (int tap = 0; tap < NT; ++tap) {
        const int xoff = XPAD - (NDLY + tap) + lane;
        f2 xs[8];
        f2 nr2 = mk2(0.f,0.f), ni2 = mk2(0.f,0.f), dd2 = mk2(0.f,0.f);
#pragma unroll
        for (int i = 0; i < 8; ++i) {
          xs[i] = xrow[xoff + 64*i];
          f2 wy = wreg[i]*yreg[i];
          nr2 += wy * xs[i];
          ni2 += wy.yx * mk2(xs[i].x, -xs[i].y);
          dd2 += (wreg[i]*xs[i]) * xs[i];
        }
        float nr = wred64(nr2.x+nr2.y), ni = wred64(ni2.x+ni2.y), dd = wred64(dd2.x+dd2.y);
        f2 vc = (1.0f/fmaxf(dd, EPSF)) * mk2(nr, ni);
#pragma unroll
        for (int i = 0; i < 8; ++i) yreg[i] -= cmul(vc, xs[i]);
      }
    }
  }

  // ================= epilogue =================
  {
    const size_t yb = ((size_t)(b*NS + wv)*NFQ + f)*NFR;
    if (last) {
#pragma unroll
      for (int i = 0; i < 8; ++i) { int n = lane+64*i; if (n < NFR) outR[yb+n] = yreg[i].x; }
    } else {
#pragma unroll
      for (int i = 0; i < 8; ++i) { int n = lane+64*i; if (n < NFR) Yg[yb+n] = yreg[i]; }
    }
  }
  if (!last) {
    __syncthreads();   // sB (GJ), sW/sJ cross-wave reads below
    for (int k = 0; k < NBK; ++k) {
      const size_t zb = ((size_t)(b*NBK+k)*NFQ + f)*NFR;
      for (int n = tid; n < NFR; n += 256) Zg[zb+n] = sZ[k][n];
    }
    if (tid < NS*NC) Wg[((size_t)(b*NS + tid/NC)*NFQ + f)*NC + tid%NC] = sW[tid/NC][tid%NC];
    else if (tid < NS*NC + NBK*NS) { int t = tid - NS*NC; Jg[((size_t)(b*NBK + t/NS)*NFQ + f)*NS + t%NS] = sJ[t/NS][t%NS]; }
    else if (tid < NS*NC + NBK*NS + NS*NS) { int t = tid - NS*NC - NBK*NS; Ag[((size_t)(b*NS + t/NS)*NFQ + f)*NS + t%NS] = sB[t/NS][NS + t%NS]; }
  }
#undef V2T
}

// ---------------------------------------------------------------------------
extern "C" void kernel_launch(void* const* d_in, const int* in_sizes, int n_in,
                              void* d_out, int out_size, void* d_ws, size_t ws_size,
                              hipStream_t stream)
{
  (void)in_sizes; (void)n_in; (void)out_size; (void)ws_size;
  const float* Xr = (const float*)d_in[0];
  const float* Xi = (const float*)d_in[1];
  float* outR = (float*)d_out;   // d_out = re(Y), float32, (2,4,320,500)

  char* ws = (char*)d_ws;
  size_t off = 0;
  f2* Yg = (f2*)(ws + off); off += (size_t)NB*NS*NFQ*NFR*sizeof(f2);   // 10,240,000
  f2* Zg = (f2*)(ws + off); off += (size_t)NB*NBK*NFQ*NFR*sizeof(f2);  //  5,120,000
  f2* Wg = (f2*)(ws + off); off += (size_t)NB*NS*NFQ*NC*sizeof(f2);    //    122,880
  f2* Jg = (f2*)(ws + off); off += (size_t)NB*NBK*NFQ*NS*sizeof(f2);   //     40,960
  f2* Ag = (f2*)(ws + off); off += (size_t)NB*NS*NFQ*NS*sizeof(f2);    //     81,920
  float* wacc = (float*)(ws + off); off += (size_t)NCH*NB*NS*NFR*sizeof(float); // 128,000
  float* wg   = (float*)(ws + off); off += (size_t)NB*NS*NFR*sizeof(float);     //  16,000

  // iter 0 (init folded in): w from X (2-stage), then fused init+iss
  k_wpartX<<<NB*NS*NCH, 512, 0, stream>>>(Xr, Xi, wacc);
  k_wfin<<<NB*NS, 512, 0, stream>>>(wacc, wg);
  k_iter<<<NB*NFQ, 256, 0, stream>>>(Xr, Xi, Yg, Zg, Wg, Jg, Ag, wg, outR, 1, 0);
  // iter 1 (last): w from Y (2-stage), then iss, write re(Y) to out
  k_wpartY<<<NB*NS*NCH, 512, 0, stream>>>(Yg, wacc);
  k_wfin<<<NB*NS, 512, 0, stream>>>(wacc, wg);
  k_iter<<<NB*NFQ, 256, 0, stream>>>(Xr, Xi, Yg, Zg, Wg, Jg, Ag, wg, outR, 0, 1);
}